// Round 18
// baseline (47.876 us; speedup 1.0000x reference)
//
#include <hip/hip_runtime.h>

// DecoderLayer: out[k,n,m] = tanh(sum_p w[k,p]*prev[idx[k,p],n,m] + b[k]),
// gated by (#active parents >= 12).  M=2048, K=4096, NN=4096 (64x64), P=16.
//
// R18 = R17 layout + per-wave modulo schedule. R12/R17 proved occupancy
// (16 vs 32 waves/CU) neutral; both pipes sit ~45% duty -> waves stall in
// LOCKSTEP phases {4 ds_reads -> wait -> FMA}. Fix: gather double-buffer
// (batch b+1 issued before batch b's FMAs, next-iter batch0 issued at bb=3
// using prefetched tables) so every wave always has 4 reads in flight.

#define M_ROWS   2048
#define K_NODES  4096
#define NN       4096
#define POS_TILE 16
#define NTHREADS 1024
#define ROW_B    40                          // bytes per padded bf16 row
#define LDS_BYTES (M_ROWS * ROW_B)           // 81920 = 80 KiB
#define OUT_ELEMS (K_NODES * NN)
#define ACTIVE_THRESHOLD 12

typedef float f32x4 __attribute__((ext_vector_type(4)));
typedef unsigned short u16x4 __attribute__((ext_vector_type(4)));

__device__ __forceinline__ float fast_tanh(float x) {
  float ax = __builtin_fabsf(x);
  float e  = __expf(-2.0f * ax);
  float r  = (1.0f - e) * __builtin_amdgcn_rcpf(1.0f + e);
  return __builtin_copysignf(r, x);
}

__device__ __forceinline__ unsigned short f2bf_rne(float f) {
  unsigned u = __float_as_uint(f);
  u += 0x7FFFu + ((u >> 16) & 1u);           // round-to-nearest-even
  return (unsigned short)(u >> 16);
}

// Gate precompute (off hot path). Runtime-detects isact marshaling:
// any 32-bit word >1 in the first 2048 bytes implies packed bytes.
__global__ __launch_bounds__(256) void act_kernel(
    const int* __restrict__ pidx, const unsigned int* __restrict__ isact,
    float* __restrict__ outact) {
  __shared__ int mode_sh;
  if (threadIdx.x == 0) mode_sh = 0;
  __syncthreads();
  int bad = 0;
  for (int i = threadIdx.x; i < 512; i += 256) bad |= (isact[i] > 1u);
  if (bad) atomicOr(&mode_sh, 1);
  __syncthreads();
  const int shift = mode_sh ? 0 : 2;   // LSB byte of a 0/1 int32 == its value
  const unsigned char* actb = (const unsigned char*)isact;

  int k = blockIdx.x * 256 + threadIdx.x;
  const int4* ip = (const int4*)(pidx + k * 16);
  int4 ia = ip[0], ib = ip[1], ic = ip[2], id4 = ip[3];
  int ids[16] = {ia.x, ia.y, ia.z, ia.w, ib.x, ib.y, ib.z, ib.w,
                 ic.x, ic.y, ic.z, ic.w, id4.x, id4.y, id4.z, id4.w};
  int n = 0;
  #pragma unroll
  for (int p = 0; p < 16; ++p) n += (actb[ids[p] << shift] != 0);
  outact[k] = (n >= ACTIVE_THRESHOLD) ? 1.0f : 0.0f;
}

// unpack-and-FMA one parent chunk: 4 bf16 positions into 4 scalar f32 accs
#define PFMA4(vv, wv)                                             \
  { float wv_ = (wv);                                             \
    a0 += wv_ * __uint_as_float((unsigned)(vv)[0] << 16);         \
    a1 += wv_ * __uint_as_float((unsigned)(vv)[1] << 16);         \
    a2 += wv_ * __uint_as_float((unsigned)(vv)[2] << 16);         \
    a3 += wv_ * __uint_as_float((unsigned)(vv)[3] << 16); }

#define GLD4(iv, d0, d1, d2, d3)                                  \
  d0 = *(const u16x4*)(xb + (iv).x * ROW_B + qb);                 \
  d1 = *(const u16x4*)(xb + (iv).y * ROW_B + qb);                 \
  d2 = *(const u16x4*)(xb + (iv).z * ROW_B + qb);                 \
  d3 = *(const u16x4*)(xb + (iv).w * ROW_B + qb);

__global__ __launch_bounds__(NTHREADS, 4) void decoder_kernel(
    const float* __restrict__ prev, const int* __restrict__ pidx,
    const float* __restrict__ w, const float* __restrict__ b,
    const float* __restrict__ actf, float* __restrict__ out) {
  extern __shared__ char xb[];               // [2048 rows][40 B] bf16 tile
  const int tid = threadIdx.x;
  const int bid = blockIdx.x;                // 0..511

  // XCD co-location: tile's two node-half blocks share an XCD (L2 reuse).
  const int xcd   = bid & 7;
  const int j     = bid >> 3;                // 0..63
  const int tile  = xcd * 32 + (j >> 1);     // 0..255
  const int half  = j & 1;
  const int pos0  = tile * POS_TILE;
  const int nbase = half * (K_NODES / 2);

  // ---- stage prev[:, pos0:pos0+16] as bf16-RNE into 40B padded rows ----
  #pragma unroll
  for (int it = 0; it < 8; ++it) {
    int ci = (it << 10) + tid;               // 0..8191
    int r = ci >> 2, c = ci & 3;
    f32x4 v = *(const f32x4*)(prev + r * NN + pos0 + (c << 2));
    u16x4 o;
    o[0] = f2bf_rne(v.x); o[1] = f2bf_rne(v.y);
    o[2] = f2bf_rne(v.z); o[3] = f2bf_rne(v.w);
    *(u16x4*)(xb + r * ROW_B + (c << 3)) = o;   // ds_write_b64
  }
  __syncthreads();

  const int q  = tid & 3;                    // chunk (4 positions) this lane owns
  const int s  = tid >> 2;                   // node slot 0..255
  const int qb = q << 3;                     // byte offset within row

  // ---- prologue: iter-0 tables + iter-0 batch-0 gathers ----
  int n0_ = nbase + s;
  const int4*   ip0 = (const int4*)(pidx + (n0_ << 4));
  const float4* wp0 = (const float4*)(w + (n0_ << 4));
  int4   ci0 = ip0[0], ci1 = ip0[1], ci2 = ip0[2], ci3 = ip0[3];
  float4 cw0 = wp0[0], cw1 = wp0[1], cw2 = wp0[2], cw3 = wp0[3];
  float  cbk = b[n0_], cg  = actf[n0_];
  u16x4 c0, c1, c2, c3;
  GLD4(ci0, c0, c1, c2, c3)

  for (int it = 0; it < 8; ++it) {
    // 1) prefetch next-iter tables (global; in flight across all 4 batches)
    int nx = nbase + (((it + 1) & 7) << 8) + s;   // wraps at it=7 (unused)
    const int4*   ipn = (const int4*)(pidx + (nx << 4));
    const float4* wpn = (const float4*)(w + (nx << 4));
    int4   ni0 = ipn[0], ni1 = ipn[1], ni2 = ipn[2], ni3 = ipn[3];
    float4 nw0 = wpn[0], nw1 = wpn[1], nw2 = wpn[2], nw3 = wpn[3];
    float  nbk = b[nx],  ng  = actf[nx];

    int n = nbase + (it << 8) + s;
    float a0 = cbk, a1 = cbk, a2 = cbk, a3 = cbk;
    u16x4 t0, t1, t2, t3;

    // bb=0: issue batch-1 reads, FMA batch-0
    GLD4(ci1, t0, t1, t2, t3)
    __builtin_amdgcn_sched_barrier(0);
    PFMA4(c0, cw0.x) PFMA4(c1, cw0.y) PFMA4(c2, cw0.z) PFMA4(c3, cw0.w)
    // bb=1: issue batch-2 reads, FMA batch-1
    GLD4(ci2, c0, c1, c2, c3)
    __builtin_amdgcn_sched_barrier(0);
    PFMA4(t0, cw1.x) PFMA4(t1, cw1.y) PFMA4(t2, cw1.z) PFMA4(t3, cw1.w)
    // bb=2: issue batch-3 reads, FMA batch-2
    GLD4(ci3, t0, t1, t2, t3)
    __builtin_amdgcn_sched_barrier(0);
    PFMA4(c0, cw2.x) PFMA4(c1, cw2.y) PFMA4(c2, cw2.z) PFMA4(c3, cw2.w)
    // bb=3: issue NEXT-ITER batch-0 reads (tables prefetched), FMA batch-3
    GLD4(ni0, c0, c1, c2, c3)
    __builtin_amdgcn_sched_barrier(0);
    PFMA4(t0, cw3.x) PFMA4(t1, cw3.y) PFMA4(t2, cw3.z) PFMA4(t3, cw3.w)

    f32x4 o;
    o.x = fast_tanh(a0) * cg;
    o.y = fast_tanh(a1) * cg;
    o.z = fast_tanh(a2) * cg;
    o.w = fast_tanh(a3) * cg;
    *(f32x4*)(out + ((size_t)n << 12) + pos0 + (q << 2)) = o;

    // rotate tables (SSA renames)
    ci0 = ni0; ci1 = ni1; ci2 = ni2; ci3 = ni3;
    cw0 = nw0; cw1 = nw1; cw2 = nw2; cw3 = nw3;
    cbk = nbk; cg = ng;
  }
}

extern "C" void kernel_launch(void* const* d_in, const int* in_sizes, int n_in,
                              void* d_out, int out_size, void* d_ws, size_t ws_size,
                              hipStream_t stream) {
  const float* prev  = (const float*)d_in[0];
  const void*  isact = d_in[1];
  const int*   pidx  = (const int*)d_in[2];
  const float* w     = (const float*)d_in[3];
  const float* b     = (const float*)d_in[4];
  float* out    = (float*)d_out;
  float* outact = out + OUT_ELEMS;           // act_kernel writes the gate vector

  (void)hipFuncSetAttribute((const void*)decoder_kernel,
                            hipFuncAttributeMaxDynamicSharedMemorySize, LDS_BYTES);

  act_kernel<<<K_NODES / 256, 256, 0, stream>>>(
      pidx, (const unsigned int*)isact, outact);
  decoder_kernel<<<(NN / POS_TILE) * 2, NTHREADS, LDS_BYTES, stream>>>(
      prev, pidx, w, b, outact, out);
}

// Round 20
// 38.401 us; speedup vs baseline: 1.2467x; 1.2467x over previous
//
#include <hip/hip_runtime.h>

// DecoderLayer: out[k,n,m] = tanh(sum_p w[k,p]*prev[idx[k,p],n,m] + b[k]),
// gated by (#active parents >= 12).  M=2048, K=4096, NN=4096 (64x64), P=16.
//
// R20 = R19 with the launch-killing bug fixed: static __shared__ mode_sh
// (4B) on top of 163840B dynamic LDS exceeded the 160KiB workgroup limit.
// The vote flag now lives in a free pad byte of the tile (*(int*)(xb+76)).
// Structure: R12 main loop (bf16 tile, 80B rows, lane-quad, 1024thr) +
// gate fused into setup (pad 72: isact byte/entry; pad 64: gate/node).
// Plateau note: 2048 gather wave-instrs/CU = information minimum
// (512MB bf16 / 1KB-instr / 256 CU) at measured ~46cyc each -> ~39us
// formulation floor; this round only removes the act_kernel dispatch.

#define M_ROWS   2048
#define K_NODES  4096
#define NN       4096
#define POS_TILE 32
#define NTHREADS 1024
#define ROW_B    80                          // 64B bf16 data + 16B pad
#define LDS_BYTES (M_ROWS * ROW_B)           // 163840 = 160 KiB (exact max)
#define OUT_ELEMS (K_NODES * NN)
#define ACTIVE_THRESHOLD 12

typedef float f32x4 __attribute__((ext_vector_type(4)));
typedef unsigned short u16x8 __attribute__((ext_vector_type(8)));

__device__ __forceinline__ float fast_tanh(float x) {
  float ax = __builtin_fabsf(x);
  float e  = __expf(-2.0f * ax);
  float r  = (1.0f - e) * __builtin_amdgcn_rcpf(1.0f + e);
  return __builtin_copysignf(r, x);
}

__device__ __forceinline__ unsigned short f2bf_rne(float f) {
  unsigned u = __float_as_uint(f);
  u += 0x7FFFu + ((u >> 16) & 1u);           // round-to-nearest-even
  return (unsigned short)(u >> 16);
}

// unpack-and-FMA one parent: 8 bf16 positions, scalar f32 accs
#define PFMA(vv, wv)                                              \
  { float wv_ = (wv);                                             \
    a0 += wv_ * __uint_as_float((unsigned)(vv)[0] << 16);         \
    a1 += wv_ * __uint_as_float((unsigned)(vv)[1] << 16);         \
    a2 += wv_ * __uint_as_float((unsigned)(vv)[2] << 16);         \
    a3 += wv_ * __uint_as_float((unsigned)(vv)[3] << 16);         \
    a4 += wv_ * __uint_as_float((unsigned)(vv)[4] << 16);         \
    a5 += wv_ * __uint_as_float((unsigned)(vv)[5] << 16);         \
    a6 += wv_ * __uint_as_float((unsigned)(vv)[6] << 16);         \
    a7 += wv_ * __uint_as_float((unsigned)(vv)[7] << 16); }

__global__ __launch_bounds__(NTHREADS, 1) void decoder_kernel(
    const float* __restrict__ prev, const unsigned int* __restrict__ isact,
    const int* __restrict__ pidx, const float* __restrict__ w,
    const float* __restrict__ b, float* __restrict__ out,
    float* __restrict__ outact) {
  extern __shared__ char xb[];               // [2048 rows][80 B]; NO static LDS
  int* modep = (int*)(xb + 76);              // vote flag in row-0 pad (4-aligned)
  const int tid = threadIdx.x;
  const int bid = blockIdx.x;                // 0..255
  if (tid == 0) *modep = 0;

  // XCD co-location (R12-proven): tile's two node-half blocks share an XCD.
  const int xcd   = bid & 7;
  const int loc   = bid >> 3;                // 0..31
  const int tile  = xcd * 16 + (loc >> 1);   // 0..127
  const int half  = loc & 1;
  const int pos0  = tile * POS_TILE;
  const int nbase = half * (K_NODES / 2);

  // ---- phase A: stage prev[:, pos0:pos0+32] as bf16-RNE (data 0..63) ----
  #pragma unroll
  for (int it = 0; it < 8; ++it) {
    int ci = (it << 10) + tid;               // 0..8191 (= r*4+c)
    int r = ci >> 2, c = ci & 3;
    const float* sp = prev + r * NN + pos0 + (c << 3);
    f32x4 v0 = *(const f32x4*)sp;
    f32x4 v1 = *(const f32x4*)(sp + 4);
    u16x8 o;
    o[0] = f2bf_rne(v0.x); o[1] = f2bf_rne(v0.y);
    o[2] = f2bf_rne(v0.z); o[3] = f2bf_rne(v0.w);
    o[4] = f2bf_rne(v1.x); o[5] = f2bf_rne(v1.y);
    o[6] = f2bf_rne(v1.z); o[7] = f2bf_rne(v1.w);
    *(u16x8*)(xb + r * ROW_B + (c << 4)) = o;
  }
  __syncthreads();                           // *modep init + tile visible

  // ---- phase B: marshaling vote (word >1 in first 512 words => bytes) ----
  if (tid < 512 && isact[tid] > 1u) atomicOr(modep, 1);
  __syncthreads();
  const int bytemode = *modep;

  // ---- phase C: normalized isact bytes into pads (entry e -> e*80+72) ----
  if (tid < 512) {
    if (bytemode) {
      unsigned wv = isact[tid];              // entries 4t..4t+3 packed
      xb[(4 * tid + 0) * ROW_B + 72] = (unsigned char)(wv);
      xb[(4 * tid + 1) * ROW_B + 72] = (unsigned char)(wv >> 8);
      xb[(4 * tid + 2) * ROW_B + 72] = (unsigned char)(wv >> 16);
      xb[(4 * tid + 3) * ROW_B + 72] = (unsigned char)(wv >> 24);
    } else {
      int4 wv4 = ((const int4*)isact)[tid];  // entries 4t..4t+3 as words
      xb[(4 * tid + 0) * ROW_B + 72] = (unsigned char)wv4.x;
      xb[(4 * tid + 1) * ROW_B + 72] = (unsigned char)wv4.y;
      xb[(4 * tid + 2) * ROW_B + 72] = (unsigned char)wv4.z;
      xb[(4 * tid + 3) * ROW_B + 72] = (unsigned char)wv4.w;
    }
  }
  __syncthreads();

  // ---- phase D: gates for this block's 2048 nodes (2 per thread) ----
  #pragma unroll
  for (int h = 0; h < 2; ++h) {
    int m = (h << 10) + tid;                 // block-local node 0..2047
    int nn_ = nbase + m;
    const int4* ip = (const int4*)(pidx + (nn_ << 4));
    int4 i0 = ip[0], i1 = ip[1], i2 = ip[2], i3 = ip[3];
    int cnt =
      (xb[i0.x * ROW_B + 72] != 0) + (xb[i0.y * ROW_B + 72] != 0) +
      (xb[i0.z * ROW_B + 72] != 0) + (xb[i0.w * ROW_B + 72] != 0) +
      (xb[i1.x * ROW_B + 72] != 0) + (xb[i1.y * ROW_B + 72] != 0) +
      (xb[i1.z * ROW_B + 72] != 0) + (xb[i1.w * ROW_B + 72] != 0) +
      (xb[i2.x * ROW_B + 72] != 0) + (xb[i2.y * ROW_B + 72] != 0) +
      (xb[i2.z * ROW_B + 72] != 0) + (xb[i2.w * ROW_B + 72] != 0) +
      (xb[i3.x * ROW_B + 72] != 0) + (xb[i3.y * ROW_B + 72] != 0) +
      (xb[i3.z * ROW_B + 72] != 0) + (xb[i3.w * ROW_B + 72] != 0);
    unsigned char gg = (cnt >= ACTIVE_THRESHOLD) ? 1 : 0;
    xb[m * ROW_B + 64] = gg;                 // gate byte in pad (offset 64)
    if (tile == 0) outact[nn_] = (float)gg;  // bids 0 & 8 cover all nodes
  }
  __syncthreads();

  // ---- main loop: R12 verbatim, gate from LDS pad ----
  const int q  = tid & 3;                    // 16B chunk = 8 positions
  const int s  = tid >> 2;                   // node slot 0..255
  const int qb = q << 4;                     // byte offset within row

  for (int it = 0; it < 8; ++it) {
    int m = (it << 8) + s;                   // block-local node
    int n = nbase + m;
    const int4*   ip = (const int4*)(pidx + (n << 4));
    const float4* wp = (const float4*)(w + (n << 4));
    int4   i0 = ip[0], i1 = ip[1], i2 = ip[2], i3 = ip[3];
    float4 w0 = wp[0], w1 = wp[1], w2 = wp[2], w3 = wp[3];
    float  bk = b[n];
    float  g  = xb[m * ROW_B + 64] ? 1.0f : 0.0f;   // quad-broadcast u8

    float a0 = bk, a1 = bk, a2 = bk, a3 = bk;
    float a4 = bk, a5 = bk, a6 = bk, a7 = bk;

    // batch 1: parents 0..7 — 8 independent ds_read_b128
    u16x8 v0 = *(const u16x8*)(xb + i0.x * ROW_B + qb);
    u16x8 v1 = *(const u16x8*)(xb + i0.y * ROW_B + qb);
    u16x8 v2 = *(const u16x8*)(xb + i0.z * ROW_B + qb);
    u16x8 v3 = *(const u16x8*)(xb + i0.w * ROW_B + qb);
    u16x8 v4 = *(const u16x8*)(xb + i1.x * ROW_B + qb);
    u16x8 v5 = *(const u16x8*)(xb + i1.y * ROW_B + qb);
    u16x8 v6 = *(const u16x8*)(xb + i1.z * ROW_B + qb);
    u16x8 v7 = *(const u16x8*)(xb + i1.w * ROW_B + qb);
    __builtin_amdgcn_sched_barrier(0);       // keep 8 reads in flight
    PFMA(v0, w0.x) PFMA(v1, w0.y) PFMA(v2, w0.z) PFMA(v3, w0.w)
    PFMA(v4, w1.x) PFMA(v5, w1.y) PFMA(v6, w1.z) PFMA(v7, w1.w)

    // batch 2: parents 8..15
    v0 = *(const u16x8*)(xb + i2.x * ROW_B + qb);
    v1 = *(const u16x8*)(xb + i2.y * ROW_B + qb);
    v2 = *(const u16x8*)(xb + i2.z * ROW_B + qb);
    v3 = *(const u16x8*)(xb + i2.w * ROW_B + qb);
    v4 = *(const u16x8*)(xb + i3.x * ROW_B + qb);
    v5 = *(const u16x8*)(xb + i3.y * ROW_B + qb);
    v6 = *(const u16x8*)(xb + i3.z * ROW_B + qb);
    v7 = *(const u16x8*)(xb + i3.w * ROW_B + qb);
    __builtin_amdgcn_sched_barrier(0);
    PFMA(v0, w2.x) PFMA(v1, w2.y) PFMA(v2, w2.z) PFMA(v3, w2.w)
    PFMA(v4, w3.x) PFMA(v5, w3.y) PFMA(v6, w3.z) PFMA(v7, w3.w)

    f32x4 o0, o1;
    o0.x = fast_tanh(a0) * g; o0.y = fast_tanh(a1) * g;
    o0.z = fast_tanh(a2) * g; o0.w = fast_tanh(a3) * g;
    o1.x = fast_tanh(a4) * g; o1.y = fast_tanh(a5) * g;
    o1.z = fast_tanh(a6) * g; o1.w = fast_tanh(a7) * g;

    // quad writes 128B contiguous of out row n (full 64B lines per pair)
    float* op = out + ((size_t)n << 12) + pos0 + (q << 3);
    *(f32x4*)op       = o0;
    *(f32x4*)(op + 4) = o1;
  }
}

extern "C" void kernel_launch(void* const* d_in, const int* in_sizes, int n_in,
                              void* d_out, int out_size, void* d_ws, size_t ws_size,
                              hipStream_t stream) {
  const float* prev  = (const float*)d_in[0];
  const void*  isact = d_in[1];
  const int*   pidx  = (const int*)d_in[2];
  const float* w     = (const float*)d_in[3];
  const float* b     = (const float*)d_in[4];
  float* out    = (float*)d_out;
  float* outact = out + OUT_ELEMS;

  (void)hipFuncSetAttribute((const void*)decoder_kernel,
                            hipFuncAttributeMaxDynamicSharedMemorySize, LDS_BYTES);

  decoder_kernel<<<(NN / POS_TILE) * 2, NTHREADS, LDS_BYTES, stream>>>(
      prev, (const unsigned int*)isact, pidx, w, b, out, outact);
}